// Round 2
// baseline (85.996 us; speedup 1.0000x reference)
//
#include <hip/hip_runtime.h>

// FlexChannelPConv2D — MI355X fp32, v2.
//
// Static facts (C_IN=8, H=W=40, B=4, ksize=5):
//   3 rings (R,sigma) = (0,.6),(1,.6),(2,.4); kept basis per channel, in order:
//   (r0,f0)(r1,f0)(r1,f1)(r2,f0)(r2,f1)(r2,f2)  -> FSEL=48 rows, COUT=36,
//   NNZ=576, col row-counts <= 24.
//   Envelope < 2e-10 for |offset| >= 5 -> 9x9 window, error ~1e-6 << 8e-2.
//   Angles need no trig: cos=dx/r, sin=dy/r, double-angle for f=2.
//
// v2 structure (v1 was 200 blocks -> occupancy/latency-bound at 85 us):
//   init kernel (1 block): build zero-padded col-major weight table in d_ws.
//   main kernel: 1600 blocks x 256 thr; block = one q, wave = one (q,b),
//   lane = (tap_group[8] x channel[8]); 11 predicated coalesced tap rounds,
//   shfl_xor(8/16/32) reduction, LDS pp staging, branchless 24-iter epilogue.

#define HGRID 40
#define WGRID 40
#define NQ    1600
#define NB    4
#define NC    8
#define COUT  36
#define NNZ   576
#define FSEL  48
#define WIN   4
#define WTAB  9
#define NTAP  81
#define MAXROW 24

__global__ __launch_bounds__(576)
void flex_init_wtab(const float* __restrict__ weights,   // [576][2]
                    const int*   __restrict__ conn_rows, // [576]
                    const int*   __restrict__ conn_cols, // [576]
                    int*   __restrict__ wrow,            // [24][36] zero-padded
                    float* __restrict__ wre,             // [24][36]
                    float* __restrict__ wim)             // [24][36]
{
    __shared__ int cnt[COUT];
    const int tid = threadIdx.x;
    if (tid < COUT) cnt[tid] = 0;
    for (int i = tid; i < MAXROW * COUT; i += 576) {
        wrow[i] = 0; wre[i] = 0.f; wim[i] = 0.f;
    }
    __syncthreads();
    if (tid < NNZ) {
        const int col  = conn_cols[tid];
        const int slot = atomicAdd(&cnt[col], 1);   // order within col irrelevant
        wrow[slot * COUT + col] = conn_rows[tid];
        wre [slot * COUT + col] = weights[2 * tid];
        wim [slot * COUT + col] = weights[2 * tid + 1];
    }
}

__global__ __launch_bounds__(256)
void flex_main(const float* __restrict__ data,    // [4][1600][8]
               const float* __restrict__ brad,    // [9]
               const float* __restrict__ bsig,    // [9]
               const float* __restrict__ premul,  // [48][2]
               const int*   __restrict__ out_rot, // [36]
               const int*   __restrict__ wrow,    // [24][36]
               const float* __restrict__ wre,     // [24][36]
               const float* __restrict__ wim,     // [24][36]
               float*       __restrict__ out)     // [4][1600][36][2]
{
    __shared__ float tab[NTAP][8];        // E0,E1,E2,c1,s1,c2,s2,pad
    __shared__ float ppb[NB][FSEL][2];    // premul-applied pp for this q

    const int tid = threadIdx.x;

    // ---- offset table (81 threads) ----
    if (tid < NTAP) {
        const int dy = tid / WTAB - WIN;
        const int dx = tid % WTAB - WIN;
        const float fy = (float)dy, fx = (float)dx;
        const float r2 = fy * fy + fx * fx;
        const float r  = sqrtf(r2);
        const float inv_s2 = 0.70710678118654752f;
        const float R0 = brad[0], S0 = bsig[0];
        const float R1 = brad[1], S1 = bsig[1];
        const float R2 = brad[4], S2 = bsig[4];
        const float t0 = (r - R0) * inv_s2 / S0;
        const float t1 = (r - R1) * inv_s2 / S1;
        const float t2 = (r - R2) * inv_s2 / S2;
        const float e0 = expf(-t0 * t0);
        const float e1 = expf(-t1 * t1);
        const float e2 = expf(-t2 * t2);
        float c1 = 0.f, s1 = 0.f, c2v = 0.f, s2v = 0.f;
        if (r2 > 0.f) {
            const float ir = 1.f / r;
            c1 = fx * ir; s1 = fy * ir;
            c2v = c1 * c1 - s1 * s1;
            s2v = 2.f * c1 * s1;
        }
        tab[tid][0] = e0;  tab[tid][1] = e1;  tab[tid][2] = e2;  tab[tid][3] = c1;
        tab[tid][4] = s1;  tab[tid][5] = c2v; tab[tid][6] = s2v; tab[tid][7] = 0.f;
    }
    __syncthreads();

    const int q  = blockIdx.x;
    const int qy = q / WGRID;
    const int qx = q - qy * WGRID;

    const int b    = tid >> 6;          // wave id = batch
    const int lane = tid & 63;
    const int c    = lane & 7;          // channel
    const int tg   = lane >> 3;         // tap group 0..7

    float p0 = 0.f, p1 = 0.f, p3 = 0.f;     // f=0 (purely real)
    float p2r = 0.f, p2i = 0.f;             // ring1 f=1
    float p4r = 0.f, p4i = 0.f;             // ring2 f=1
    float p5r = 0.f, p5i = 0.f;             // ring2 f=2

    const int base_bc = b * NQ * NC + c;
    #pragma unroll
    for (int round = 0; round < 11; ++round) {
        const int t = tg + round * 8;
        if (t < NTAP) {
            const int dy = t / WTAB - WIN;
            const int dx = t - (dy + WIN) * WTAB - WIN;
            const int py = qy + dy;
            const int px = qx + dx;
            const bool ok = (py >= 0) & (py < HGRID) & (px >= 0) & (px < WGRID);
            float d = 0.f;
            if (ok) d = data[base_bc + (py * WGRID + px) * NC];
            const float4 tA = *(const float4*)&tab[t][0];
            const float4 tB = *(const float4*)&tab[t][4];
            p0 += d * tA.x;
            p1 += d * tA.y;
            p3 += d * tA.z;
            const float dc1 = d * tA.w, ds1 = d * tB.x;
            const float dc2 = d * tB.y, ds2 = d * tB.z;
            p2r += dc1 * tA.y; p2i += ds1 * tA.y;
            p4r += dc1 * tA.z; p4i += ds1 * tA.z;
            p5r += dc2 * tA.z; p5i += ds2 * tA.z;
        }
    }

    // reduce across the 8 tap groups (lanes with equal c are 8 apart)
    #pragma unroll
    for (int m = 8; m <= 32; m <<= 1) {
        p0  += __shfl_xor(p0, m);  p1  += __shfl_xor(p1, m);
        p3  += __shfl_xor(p3, m);
        p2r += __shfl_xor(p2r, m); p2i += __shfl_xor(p2i, m);
        p4r += __shfl_xor(p4r, m); p4i += __shfl_xor(p4i, m);
        p5r += __shfl_xor(p5r, m); p5i += __shfl_xor(p5i, m);
    }

    if (tg == 0) {
        const int kb = c * 6;
        ppb[b][kb + 0][0] = p0  * premul[(kb + 0) * 2];  ppb[b][kb + 0][1] = 0.f;
        ppb[b][kb + 1][0] = p1  * premul[(kb + 1) * 2];  ppb[b][kb + 1][1] = 0.f;
        ppb[b][kb + 2][0] = p2r * premul[(kb + 2) * 2];
        ppb[b][kb + 2][1] = p2i * premul[(kb + 2) * 2 + 1];
        ppb[b][kb + 3][0] = p3  * premul[(kb + 3) * 2];  ppb[b][kb + 3][1] = 0.f;
        ppb[b][kb + 4][0] = p4r * premul[(kb + 4) * 2];
        ppb[b][kb + 4][1] = p4i * premul[(kb + 4) * 2 + 1];
        ppb[b][kb + 5][0] = p5r * premul[(kb + 5) * 2];
        ppb[b][kb + 5][1] = p5i * premul[(kb + 5) * 2 + 1];
    }
    __syncthreads();

    // ---- epilogue: sparse complex mixing, branchless 24-iter loop ----
    const int co = lane;                 // 0..35 active
    if (co < COUT) {
        float are = 0.f, aim = 0.f;
        #pragma unroll 4
        for (int i = 0; i < MAXROW; ++i) {
            const int   k  = wrow[i * COUT + co];
            const float wr = wre [i * COUT + co];
            const float wi = wim [i * COUT + co];
            const float pr = ppb[b][k][0];
            const float pi = ppb[b][k][1];
            are += pr * wr - pi * wi;    // padded slots: wr=wi=0 -> no-op
            aim += pr * wi + pi * wr;
        }
        if (out_rot[co] == 0) aim = 0.f;
        float2* o2 = (float2*)out;
        o2[(b * NQ + q) * COUT + co] = make_float2(are, aim);
    }
}

extern "C" void kernel_launch(void* const* d_in, const int* in_sizes, int n_in,
                              void* d_out, int out_size, void* d_ws, size_t ws_size,
                              hipStream_t stream) {
    const float* data      = (const float*)d_in[0];
    // d_in[1] = inp_grid (implicit: unit-spacing integer grid)
    const float* weights   = (const float*)d_in[2];
    const float* brad      = (const float*)d_in[3];
    const float* bsig      = (const float*)d_in[4];
    // d_in[5] = basis_frequency (implicit in kept-basis structure)
    const float* premul    = (const float*)d_in[6];
    // d_in[7] = pre_cut_idx (implicit: kept order is c-major, basis-ascending)
    const int*   conn_rows = (const int*)d_in[8];
    const int*   conn_cols = (const int*)d_in[9];
    const int*   out_rot   = (const int*)d_in[10];
    float* out = (float*)d_out;

    int*   wrow = (int*)d_ws;
    float* wre  = (float*)((char*)d_ws + MAXROW * COUT * sizeof(int));
    float* wim  = (float*)((char*)d_ws + 2 * MAXROW * COUT * sizeof(int));

    flex_init_wtab<<<1, 576, 0, stream>>>(weights, conn_rows, conn_cols,
                                          wrow, wre, wim);
    flex_main<<<NQ, 256, 0, stream>>>(data, brad, bsig, premul, out_rot,
                                      wrow, wre, wim, out);
}

// Round 4
// 85.748 us; speedup vs baseline: 1.0029x; 1.0029x over previous
//
#include <hip/hip_runtime.h>

// FlexChannelPConv2D — MI355X fp32, v3 (single dispatch).
//
// Static facts (C_IN=8, H=W=40, B=4, ksize=5):
//   3 rings (R,sigma) = (0,.6),(1,.6),(2,.4); kept basis per channel, order
//   (r0,f0)(r1,f0)(r1,f1)(r2,f0)(r2,f1)(r2,f2) -> FSEL=48 rows, COUT=36,
//   NNZ=576, per-column row count <= 24.
//   Envelope < 2e-10 for |offset| >= 5 -> 9x9 window, trunc err ~1e-6 << 8e-2.
//   Angles need no trig: cos=dx/r, sin=dy/r, double-angle for f=2.
//
// v3: dur_us is dominated by ~80us of harness re-poison fills (256 MiB d_ws
// 0xAA memsets at ~6.7 TB/s appear as the only >39us dispatches in rocprof;
// our kernels never rank). Controllable slice is ~6us. So: fold the weight
// scatter into the main kernel (LDS atomics, overlapped with tap loads) to
// kill the serial 1-block init dispatch and its launch overhead.

#define HGRID 40
#define WGRID 40
#define NQ    1600
#define NB    4
#define NC    8
#define COUT  36
#define NNZ   576
#define FSEL  48
#define WIN   4
#define WTAB  9
#define NTAP  81
#define MAXROW 24

__global__ __launch_bounds__(256)
void flex_main(const float* __restrict__ data,      // [4][1600][8]
               const float* __restrict__ weights,   // [576][2]
               const float* __restrict__ brad,      // [9]
               const float* __restrict__ bsig,      // [9]
               const float* __restrict__ premul,    // [48][2]
               const int*   __restrict__ conn_rows, // [576]
               const int*   __restrict__ conn_cols, // [576]
               const int*   __restrict__ out_rot,   // [36]
               float*       __restrict__ out)       // [4][1600][36][2]
{
    __shared__ float tab[NTAP][8];        // E0,E1,E2,c1,s1,c2,s2,pad
    __shared__ float ppb[NB][FSEL][2];    // premul-applied pp for this q
    __shared__ int   cnt[COUT];
    __shared__ int   colRow[MAXROW][COUT];
    __shared__ float colWre[MAXROW][COUT];
    __shared__ float colWim[MAXROW][COUT];

    const int tid = threadIdx.x;

    // ---- phase A: zero col counters + pad weight slots + offset table ----
    if (tid < COUT) cnt[tid] = 0;
    for (int i = tid; i < MAXROW * COUT; i += 256) {
        colRow[0][i] = 0;   // flat index into [MAXROW][COUT]
        colWre[0][i] = 0.f;
        colWim[0][i] = 0.f;
    }
    if (tid < NTAP) {
        const int dy = tid / WTAB - WIN;
        const int dx = tid % WTAB - WIN;
        const float fy = (float)dy, fx = (float)dx;
        const float r2 = fy * fy + fx * fx;
        const float r  = sqrtf(r2);
        const float inv_s2 = 0.70710678118654752f;
        const float R0 = brad[0], S0 = bsig[0];
        const float R1 = brad[1], S1 = bsig[1];
        const float R2 = brad[4], S2 = bsig[4];
        const float t0 = (r - R0) * inv_s2 / S0;
        const float t1 = (r - R1) * inv_s2 / S1;
        const float t2 = (r - R2) * inv_s2 / S2;
        const float e0 = expf(-t0 * t0);
        const float e1 = expf(-t1 * t1);
        const float e2 = expf(-t2 * t2);
        float c1 = 0.f, s1 = 0.f, c2v = 0.f, s2v = 0.f;
        if (r2 > 0.f) {
            const float ir = 1.f / r;
            c1 = fx * ir; s1 = fy * ir;
            c2v = c1 * c1 - s1 * s1;
            s2v = 2.f * c1 * s1;
        }
        tab[tid][0] = e0;  tab[tid][1] = e1;  tab[tid][2] = e2;  tab[tid][3] = c1;
        tab[tid][4] = s1;  tab[tid][5] = c2v; tab[tid][6] = s2v; tab[tid][7] = 0.f;
    }
    __syncthreads();

    // ---- phase B1: weight scatter (independent of taps; overlaps them) ----
    for (int n = tid; n < NNZ; n += 256) {
        const int col  = conn_cols[n];
        const int slot = atomicAdd(&cnt[col], 1);   // in-col order irrelevant
        colRow[slot][col] = conn_rows[n];
        colWre[slot][col] = weights[2 * n];
        colWim[slot][col] = weights[2 * n + 1];
    }

    // ---- phase B2: windowed accumulation ----
    const int q  = blockIdx.x;
    const int qy = q / WGRID;
    const int qx = q - qy * WGRID;

    const int b    = tid >> 6;          // wave id = batch
    const int lane = tid & 63;
    const int c    = lane & 7;          // channel
    const int tg   = lane >> 3;         // tap group 0..7

    float p0 = 0.f, p1 = 0.f, p3 = 0.f;     // f=0 (purely real)
    float p2r = 0.f, p2i = 0.f;             // ring1 f=1
    float p4r = 0.f, p4i = 0.f;             // ring2 f=1
    float p5r = 0.f, p5i = 0.f;             // ring2 f=2

    const int base_bc = b * NQ * NC + c;
    #pragma unroll
    for (int round = 0; round < 11; ++round) {
        const int t = tg + round * 8;
        if (t < NTAP) {
            const int dy = t / WTAB - WIN;
            const int dx = t - (dy + WIN) * WTAB - WIN;
            const int py = qy + dy;
            const int px = qx + dx;
            const bool ok = (py >= 0) & (py < HGRID) & (px >= 0) & (px < WGRID);
            float d = 0.f;
            if (ok) d = data[base_bc + (py * WGRID + px) * NC];
            const float4 tA = *(const float4*)&tab[t][0];
            const float4 tB = *(const float4*)&tab[t][4];
            p0 += d * tA.x;
            p1 += d * tA.y;
            p3 += d * tA.z;
            const float dc1 = d * tA.w, ds1 = d * tB.x;
            const float dc2 = d * tB.y, ds2 = d * tB.z;
            p2r += dc1 * tA.y; p2i += ds1 * tA.y;
            p4r += dc1 * tA.z; p4i += ds1 * tA.z;
            p5r += dc2 * tA.z; p5i += ds2 * tA.z;
        }
    }

    // reduce across the 8 tap groups (lanes with equal c are 8 apart)
    #pragma unroll
    for (int m = 8; m <= 32; m <<= 1) {
        p0  += __shfl_xor(p0, m);  p1  += __shfl_xor(p1, m);
        p3  += __shfl_xor(p3, m);
        p2r += __shfl_xor(p2r, m); p2i += __shfl_xor(p2i, m);
        p4r += __shfl_xor(p4r, m); p4i += __shfl_xor(p4i, m);
        p5r += __shfl_xor(p5r, m); p5i += __shfl_xor(p5i, m);
    }

    if (tg == 0) {
        const int kb = c * 6;
        ppb[b][kb + 0][0] = p0  * premul[(kb + 0) * 2];  ppb[b][kb + 0][1] = 0.f;
        ppb[b][kb + 1][0] = p1  * premul[(kb + 1) * 2];  ppb[b][kb + 1][1] = 0.f;
        ppb[b][kb + 2][0] = p2r * premul[(kb + 2) * 2];
        ppb[b][kb + 2][1] = p2i * premul[(kb + 2) * 2 + 1];
        ppb[b][kb + 3][0] = p3  * premul[(kb + 3) * 2];  ppb[b][kb + 3][1] = 0.f;
        ppb[b][kb + 4][0] = p4r * premul[(kb + 4) * 2];
        ppb[b][kb + 4][1] = p4i * premul[(kb + 4) * 2 + 1];
        ppb[b][kb + 5][0] = p5r * premul[(kb + 5) * 2];
        ppb[b][kb + 5][1] = p5i * premul[(kb + 5) * 2 + 1];
    }
    __syncthreads();

    // ---- phase C: sparse complex mixing, branchless 24-iter loop ----
    const int co = lane;                 // 0..35 active
    if (co < COUT) {
        float are = 0.f, aim = 0.f;
        #pragma unroll 4
        for (int i = 0; i < MAXROW; ++i) {
            const int   k  = colRow[i][co];
            const float wr = colWre[i][co];
            const float wi = colWim[i][co];
            const float pr = ppb[b][k][0];
            const float pi = ppb[b][k][1];
            are += pr * wr - pi * wi;    // padded slots: wr=wi=0 -> no-op
            aim += pr * wi + pi * wr;
        }
        if (out_rot[co] == 0) aim = 0.f;
        float2* o2 = (float2*)out;
        o2[(b * NQ + q) * COUT + co] = make_float2(are, aim);
    }
}

extern "C" void kernel_launch(void* const* d_in, const int* in_sizes, int n_in,
                              void* d_out, int out_size, void* d_ws, size_t ws_size,
                              hipStream_t stream) {
    const float* data      = (const float*)d_in[0];
    // d_in[1] = inp_grid (implicit: unit-spacing integer grid)
    const float* weights   = (const float*)d_in[2];
    const float* brad      = (const float*)d_in[3];
    const float* bsig      = (const float*)d_in[4];
    // d_in[5] = basis_frequency (implicit in kept-basis structure)
    const float* premul    = (const float*)d_in[6];
    // d_in[7] = pre_cut_idx (implicit: kept order is c-major, basis-ascending)
    const int*   conn_rows = (const int*)d_in[8];
    const int*   conn_cols = (const int*)d_in[9];
    const int*   out_rot   = (const int*)d_in[10];
    float* out = (float*)d_out;

    flex_main<<<NQ, 256, 0, stream>>>(data, weights, brad, bsig, premul,
                                      conn_rows, conn_cols, out_rot, out);
}